// Round 20
// baseline (207.021 us; speedup 1.0000x reference)
//
#include <hip/hip_runtime.h>
#include <hip/hip_bf16.h>
#include <math.h>

#define TTOK   25216      // 128*197
#define SEQL   197
#define NBATCH 128
#define DMODEL 256
#define NHEADS 8
#define FFD    1024
#define NEXP   4
#define NCLS   38
#define CONVK  768
#define NPATCH 196
#define CM     25088      // conv GEMM rows = 128*196

typedef unsigned short u16;
typedef unsigned int u32;
using s16x4 = __attribute__((ext_vector_type(4))) short;
using s16x8 = __attribute__((ext_vector_type(8))) short;
using f32x4 = __attribute__((ext_vector_type(4))) float;

__device__ __forceinline__ float b2f(u16 v) {
  union { unsigned u; float f; } x; x.u = (unsigned)v << 16; return x.f;
}
__device__ __forceinline__ u16 f2b(float f) {
  __hip_bfloat16 h = __float2bfloat16(f);
  return *reinterpret_cast<u16*>(&h);
}
__device__ __forceinline__ void gload16(const void* g, void* l) {
  __builtin_amdgcn_global_load_lds(
      (const __attribute__((address_space(1))) void*)g,
      (__attribute__((address_space(3))) void*)l, 16, 0, 0);
}
__device__ __forceinline__ float warp_sum(float v) {
  #pragma unroll
  for (int o = 32; o; o >>= 1) v += __shfl_xor(v, o);
  return v;
}
__device__ __forceinline__ float warp_max(float v) {
  #pragma unroll
  for (int o = 32; o; o >>= 1) v = fmaxf(v, __shfl_xor(v, o));
  return v;
}
__device__ __forceinline__ int fsw(int row) { return (row ^ (row >> 2)) & 3; }
__device__ __forceinline__ s16x8 ldA72(const u16* base, int rowa, int l4) {
  const char* p = (const char*)base + rowa * 72 + l4 * 16;
  s16x4 a = *(const s16x4*)p;
  s16x4 b = *(const s16x4*)(p + 8);
  return __builtin_shufflevector(a, b, 0, 1, 2, 3, 4, 5, 6, 7);
}

// ------- weight splits (384 blocks) + q_cls (block 384) + cls rows (385) -----
__global__ __launch_bounds__(256) void k_cast2b(const float* __restrict__ cw,
                                                u16* __restrict__ cwh,
                                                u16* __restrict__ cwl,
                                                const float* __restrict__ qw,
                                                u16* __restrict__ qwh,
                                                u16* __restrict__ qwl,
                                                const float* __restrict__ cls,
                                                const float* __restrict__ ln1g,
                                                const float* __restrict__ ln1b,
                                                const float* __restrict__ qb,
                                                float* __restrict__ qf,
                                                float* __restrict__ tok) {
  int bid = blockIdx.x;
  if (bid == 385) {
    // write cls rows (s==0) into tok for all batches
    float v = cls[threadIdx.x];
    for (int b = 0; b < NBATCH; ++b)
      tok[(size_t)b * SEQL * DMODEL + threadIdx.x] = v;
    return;
  }
  if (bid == 384) {
    const int n = threadIdx.x, w = n >> 6, lane = n & 63;
    __shared__ float xs[DMODEL];
    __shared__ float red[8];
    float v = cls[n];
    float s1 = warp_sum(v), s2 = warp_sum(v * v);
    if (lane == 0) { red[w] = s1; red[4 + w] = s2; }
    __syncthreads();
    s1 = red[0] + red[1] + red[2] + red[3];
    s2 = red[4] + red[5] + red[6] + red[7];
    float mu = s1 * (1.f / DMODEL);
    float var = s2 * (1.f / DMODEL) - mu * mu;
    float rs = rsqrtf(var + 1e-5f);
    xs[n] = (v - mu) * rs * ln1g[n] + ln1b[n];
    __syncthreads();
    float val = qb[n];
    #pragma unroll 4
    for (int i = 0; i < 64; ++i) {
      float4 wv = *(const float4*)(qw + (size_t)n * DMODEL + i * 4);
      val = fmaf(wv.x, xs[i * 4 + 0], val);
      val = fmaf(wv.y, xs[i * 4 + 1], val);
      val = fmaf(wv.z, xs[i * 4 + 2], val);
      val = fmaf(wv.w, xs[i * 4 + 3], val);
    }
    qf[n] = val;
    return;
  }
  const float* in = cw; u16* hi = cwh; u16* lo = cwl;
  if (bid >= 192) { bid -= 192; in = qw; hi = qwh; lo = qwl; }
  int i = (bid * 256 + threadIdx.x) * 4;
  float4 v = *(const float4*)&in[i];
  float vv[4] = {v.x, v.y, v.z, v.w};
  u16 h[4], l[4];
  #pragma unroll
  for (int j = 0; j < 4; ++j) {
    h[j] = f2b(vv[j]);
    l[j] = f2b(vv[j] - b2f(h[j]));
  }
  *(uint2*)&hi[i] = *(const uint2*)h;
  *(uint2*)&lo[i] = *(const uint2*)l;
}

// ---------------- fused im2col + split-MFMA conv GEMM, tile 128x128 ----------
__global__ __launch_bounds__(256) void k_conv(const float* __restrict__ x,
                                              const u16* __restrict__ cwh,
                                              const u16* __restrict__ cwl,
                                              const float* __restrict__ cb,
                                              float* __restrict__ tok) {
  const int n0 = blockIdx.x * 128;
  const int m0 = blockIdx.y * 128;
  __shared__ __align__(16) u16 lds[25600];   // A h/l (2*4608) + W dbuf (16384)
  u16* Ah_s = lds;
  u16* Al_s = lds + 4608;
  u16* Wbuf = lds + 9216;
  const int tid = threadIdx.x;
  const int lane = tid & 63;
  const int wv = tid >> 6;
  const int wr = wv >> 1, wc = wv & 1;
  const int l15 = lane & 15, l4 = lane >> 4;
  f32x4 acc[4][4] = {};

  const int kpos = (tid & 7) * 4;
  long abase[4]; int aldso[4];
  #pragma unroll
  for (int it = 0; it < 4; ++it) {
    int row = it * 32 + (tid >> 3);
    int m = m0 + row;
    int b = m / NPATCH, p = m - b * NPATCH;
    int py = p / 14, px = p - py * 14;
    abase[it] = (long)(b * 3) * 50176 + (py * 16) * 224 + px * 16;
    aldso[it] = row * 72 + kpos * 2;
  }
  long woff[2]; int wofs[2];
  #pragma unroll
  for (int r = 0; r < 2; ++r) {
    int off = r * 4096 + tid * 16;
    int row = off >> 6;
    int c16 = (off >> 4) & 3;
    int kk = (c16 ^ fsw(row)) << 3;
    woff[r] = (long)(n0 + row) * CONVK + kk;
    wofs[r] = off;
  }
  #pragma unroll
  for (int r = 0; r < 2; ++r) {
    gload16(cwh + woff[r], (char*)Wbuf + wofs[r]);
    gload16(cwl + woff[r], (char*)Wbuf + 8192 + wofs[r]);
  }
  float4 xr[4];
  {
    int c = kpos >> 8, r8 = kpos & 255;
    long soff = (long)c * 50176 + (r8 >> 4) * 224 + (r8 & 15);
    #pragma unroll
    for (int it = 0; it < 4; ++it) xr[it] = *(const float4*)&x[abase[it] + soff];
  }
  int cur = 0;
  for (int kc = 0; kc < CONVK; kc += 32) {
    #pragma unroll
    for (int it = 0; it < 4; ++it) {
      float vv[4] = {xr[it].x, xr[it].y, xr[it].z, xr[it].w};
      u16 h[4], l[4];
      #pragma unroll
      for (int j = 0; j < 4; ++j) {
        h[j] = f2b(vv[j]);
        l[j] = f2b(vv[j] - b2f(h[j]));
      }
      *(uint2*)((char*)Ah_s + aldso[it]) = *(const uint2*)h;
      *(uint2*)((char*)Al_s + aldso[it]) = *(const uint2*)l;
    }
    __syncthreads();                         // bar1 (ds_write visible)
    if (kc + 32 < CONVK) {                   // prefetch next W + x under MFMA
      char* wdst = (char*)Wbuf + ((cur ^ 1) << 14);
      #pragma unroll
      for (int r = 0; r < 2; ++r) {
        gload16(cwh + woff[r] + kc + 32, wdst + wofs[r]);
        gload16(cwl + woff[r] + kc + 32, wdst + 8192 + wofs[r]);
      }
      int k = kc + 32 + kpos;
      int c = k >> 8, r8 = k & 255;
      long soff = (long)c * 50176 + (r8 >> 4) * 224 + (r8 & 15);
      #pragma unroll
      for (int it = 0; it < 4; ++it) xr[it] = *(const float4*)&x[abase[it] + soff];
    }
    const char* Wcur = (const char*)Wbuf + (cur << 14);
    s16x8 ah[4], al[4], bh[4], bl[4];
    #pragma unroll
    for (int i = 0; i < 4; ++i) {
      int rowa = wr * 64 + i * 16 + l15;
      ah[i] = ldA72(Ah_s, rowa, l4);
      al[i] = ldA72(Al_s, rowa, l4);
      int rowb = wc * 64 + i * 16 + l15;
      int kbb = (l4 ^ fsw(rowb)) << 4;
      bh[i] = *(const s16x8*)(Wcur + rowb * 64 + kbb);
      bl[i] = *(const s16x8*)(Wcur + 8192 + rowb * 64 + kbb);
    }
    #pragma unroll
    for (int i = 0; i < 4; ++i)
      #pragma unroll
      for (int j = 0; j < 4; ++j)
        acc[i][j] = __builtin_amdgcn_mfma_f32_16x16x32_bf16(ah[i], bh[j],
                                                            acc[i][j], 0, 0, 0);
    #pragma unroll
    for (int i = 0; i < 4; ++i)
      #pragma unroll
      for (int j = 0; j < 4; ++j)
        acc[i][j] = __builtin_amdgcn_mfma_f32_16x16x32_bf16(ah[i], bl[j],
                                                            acc[i][j], 0, 0, 0);
    #pragma unroll
    for (int i = 0; i < 4; ++i)
      #pragma unroll
      for (int j = 0; j < 4; ++j)
        acc[i][j] = __builtin_amdgcn_mfma_f32_16x16x32_bf16(al[i], bh[j],
                                                            acc[i][j], 0, 0, 0);
    __syncthreads();                         // bar2 (drains prefetch under MFMA)
    cur ^= 1;
  }
  const int mb = m0 + wr * 64 + (l4 << 2);
  const int nb = n0 + wc * 64 + l15;
  #pragma unroll
  for (int i = 0; i < 4; ++i) {
    #pragma unroll
    for (int jf = 0; jf < 4; ++jf) {
      #pragma unroll
      for (int j = 0; j < 4; ++j) {
        int m = mb + i * 16 + j;
        int n = nb + jf * 16;
        int bq = m / NPATCH;
        long cr = (long)bq * SEQL + (m - bq * NPATCH) + 1;
        tok[cr * DMODEL + n] = acc[i][jf][j] + cb[n];
      }
    }
  }
}

// -------- fused LN1-stats + LN1 + K/V split-MFMA GEMM, tile 128x128 ----------
// prepass: 2 threads/row compute (mu, rsqrt) for the block's 128 rows (L2-hot).
__global__ __launch_bounds__(256) void k_qkv(const float* __restrict__ tok,
                                             const float* __restrict__ g,
                                             const float* __restrict__ bb,
                                             const u16* __restrict__ Wh,
                                             const u16* __restrict__ Wl,
                                             const float* __restrict__ bias,
                                             float* __restrict__ Cf) {
  const int n0 = blockIdx.x * 128;
  const int m0 = blockIdx.y * 128;
  __shared__ __align__(16) u16 lds[25600];
  __shared__ float2 stl[128];
  u16* Ah_s = lds;
  u16* Al_s = lds + 4608;
  u16* Wbuf = lds + 9216;
  const int tid = threadIdx.x;
  const int lane = tid & 63;
  const int wv = tid >> 6;
  const int wr = wv >> 1, wc = wv & 1;
  const int l15 = lane & 15, l4 = lane >> 4;
  f32x4 acc[4][4] = {};

  // ---- LN1 stats prepass: row r = tid>>1, half hf = tid&1
  {
    int r = tid >> 1, hf = tid & 1;
    const float* rp = tok + (long)(m0 + r) * DMODEL + hf * 128;
    float s1 = 0.f, s2 = 0.f;
    #pragma unroll
    for (int i = 0; i < 32; ++i) {
      float4 v = *(const float4*)(rp + i * 4);
      s1 += v.x + v.y + v.z + v.w;
      s2 += v.x * v.x + v.y * v.y + v.z * v.z + v.w * v.w;
    }
    s1 += __shfl_xor(s1, 1);
    s2 += __shfl_xor(s2, 1);
    if (hf == 0) {
      float mu = s1 * (1.f / DMODEL);
      float var = s2 * (1.f / DMODEL) - mu * mu;
      stl[r] = make_float2(mu, rsqrtf(var + 1e-5f));
    }
  }
  __syncthreads();

  const int kpos = (tid & 7) * 4;
  long atok[4]; float2 st[4]; int aldso[4];
  #pragma unroll
  for (int it = 0; it < 4; ++it) {
    int row = it * 32 + (tid >> 3);
    atok[it] = (long)(m0 + row) * DMODEL;
    st[it] = stl[row];
    aldso[it] = row * 72 + kpos * 2;
  }
  long woff[2]; int wofs[2];
  #pragma unroll
  for (int r = 0; r < 2; ++r) {
    int off = r * 4096 + tid * 16;
    int row = off >> 6;
    int c16 = (off >> 4) & 3;
    int kk = (c16 ^ fsw(row)) << 3;
    woff[r] = (long)(n0 + row) * DMODEL + kk;
    wofs[r] = off;
  }
  #pragma unroll
  for (int r = 0; r < 2; ++r) {
    gload16(Wh + woff[r], (char*)Wbuf + wofs[r]);
    gload16(Wl + woff[r], (char*)Wbuf + 8192 + wofs[r]);
  }
  float4 xr[4], gr, br;
  #pragma unroll
  for (int it = 0; it < 4; ++it) xr[it] = *(const float4*)&tok[atok[it] + kpos];
  gr = *(const float4*)&g[kpos];
  br = *(const float4*)&bb[kpos];
  int cur = 0;
  for (int kc = 0; kc < DMODEL; kc += 32) {
    float gg[4] = {gr.x, gr.y, gr.z, gr.w};
    float bbv[4] = {br.x, br.y, br.z, br.w};
    #pragma unroll
    for (int it = 0; it < 4; ++it) {
      float vv[4] = {xr[it].x, xr[it].y, xr[it].z, xr[it].w};
      u16 h[4], l[4];
      #pragma unroll
      for (int j = 0; j < 4; ++j) {
        float xd = (vv[j] - st[it].x) * st[it].y * gg[j] + bbv[j];
        h[j] = f2b(xd);
        l[j] = f2b(xd - b2f(h[j]));
      }
      *(uint2*)((char*)Ah_s + aldso[it]) = *(const uint2*)h;
      *(uint2*)((char*)Al_s + aldso[it]) = *(const uint2*)l;
    }
    __syncthreads();
    if (kc + 32 < DMODEL) {
      char* wdst = (char*)Wbuf + ((cur ^ 1) << 14);
      #pragma unroll
      for (int r = 0; r < 2; ++r) {
        gload16(Wh + woff[r] + kc + 32, wdst + wofs[r]);
        gload16(Wl + woff[r] + kc + 32, wdst + 8192 + wofs[r]);
      }
      #pragma unroll
      for (int it = 0; it < 4; ++it)
        xr[it] = *(const float4*)&tok[atok[it] + kc + 32 + kpos];
      gr = *(const float4*)&g[kc + 32 + kpos];
      br = *(const float4*)&bb[kc + 32 + kpos];
    }
    const char* Wcur = (const char*)Wbuf + (cur << 14);
    s16x8 ah[4], al[4], bh[4], bl[4];
    #pragma unroll
    for (int i = 0; i < 4; ++i) {
      int rowa = wr * 64 + i * 16 + l15;
      ah[i] = ldA72(Ah_s, rowa, l4);
      al[i] = ldA72(Al_s, rowa, l4);
      int rowb = wc * 64 + i * 16 + l15;
      int kbb = (l4 ^ fsw(rowb)) << 4;
      bh[i] = *(const s16x8*)(Wcur + rowb * 64 + kbb);
      bl[i] = *(const s16x8*)(Wcur + 8192 + rowb * 64 + kbb);
    }
    #pragma unroll
    for (int i = 0; i < 4; ++i)
      #pragma unroll
      for (int j = 0; j < 4; ++j)
        acc[i][j] = __builtin_amdgcn_mfma_f32_16x16x32_bf16(ah[i], bh[j],
                                                            acc[i][j], 0, 0, 0);
    #pragma unroll
    for (int i = 0; i < 4; ++i)
      #pragma unroll
      for (int j = 0; j < 4; ++j)
        acc[i][j] = __builtin_amdgcn_mfma_f32_16x16x32_bf16(ah[i], bl[j],
                                                            acc[i][j], 0, 0, 0);
    #pragma unroll
    for (int i = 0; i < 4; ++i)
      #pragma unroll
      for (int j = 0; j < 4; ++j)
        acc[i][j] = __builtin_amdgcn_mfma_f32_16x16x32_bf16(al[i], bh[j],
                                                            acc[i][j], 0, 0, 0);
    __syncthreads();
    cur ^= 1;
  }
  const int mb = m0 + wr * 64 + (l4 << 2);
  const int nb = n0 + wc * 64 + l15;
  #pragma unroll
  for (int i = 0; i < 4; ++i) {
    #pragma unroll
    for (int jf = 0; jf < 4; ++jf) {
      #pragma unroll
      for (int j = 0; j < 4; ++j) {
        int m = mb + i * 16 + j;
        int n = nb + jf * 16;
        Cf[(long)m * 512 + n] = acc[i][jf][j] + bias[n];
      }
    }
  }
}

// ---------------- attention v3: one block per (b,h), 256 thr -----------------
__global__ __launch_bounds__(256) void k_attn2(const float* __restrict__ qf,
                                               const float* __restrict__ kvf,
                                               float* __restrict__ aocf) {
  const int b = blockIdx.x, h = blockIdx.y;
  const int tid = threadIdx.x, w = tid >> 6, lane = tid & 63;
  __shared__ float qs[32];
  __shared__ float Ps[256];
  __shared__ float red[8];
  __shared__ float pvred[8][32];
  if (tid < 32) qs[tid] = qf[h * 32 + tid];
  __syncthreads();
  float s = -1e30f;
  if (tid < SEQL) {
    const float* kr = kvf + ((size_t)(b * SEQL + tid)) * 512 + h * 32;
    float a = 0.f;
    #pragma unroll
    for (int i = 0; i < 8; ++i) {
      float4 k4 = *(const float4*)(kr + i * 4);
      a = fmaf(k4.x, qs[i * 4 + 0], a);
      a = fmaf(k4.y, qs[i * 4 + 1], a);
      a = fmaf(k4.z, qs[i * 4 + 2], a);
      a = fmaf(k4.w, qs[i * 4 + 3], a);
    }
    s = a * 0.17677669529663687f;  // 1/sqrt(32)
  }
  float mx = warp_max(s);
  if (lane == 0) red[w] = mx;
  __syncthreads();
  mx = fmaxf(fmaxf(red[0], red[1]), fmaxf(red[2], red[3]));
  float e = (tid < SEQL) ? __expf(s - mx) : 0.f;
  float ssum = warp_sum(e);
  if (lane == 0) red[4 + w] = ssum;
  __syncthreads();
  float inv = 1.f / (red[4] + red[5] + red[6] + red[7]);
  Ps[tid] = e * inv;
  __syncthreads();
  const int d = tid & 31, kq = tid >> 5;
  float acc = 0.f;
  const int kbeg = kq * 25;
  #pragma unroll 5
  for (int i = 0; i < 25; ++i) {
    int k = kbeg + i;
    if (k < SEQL)
      acc = fmaf(Ps[k], kvf[((size_t)(b * SEQL + k)) * 512 + 256 + h * 32 + d], acc);
  }
  pvred[kq][d] = acc;
  __syncthreads();
  if (tid < 32) {
    float r = 0.f;
    #pragma unroll
    for (int j = 0; j < 8; ++j) r += pvred[j][tid];
    aocf[b * DMODEL + h * 32 + tid] = r;
  }
}

// ---------------- fused oproj + residual(cls) + LN2 + router + MoE1 ----------
__global__ __launch_bounds__(512) void k_tail2(
    const float* __restrict__ aocf,
    const float* __restrict__ ow, const float* __restrict__ ob,
    const float* __restrict__ cls,
    const float* __restrict__ g, const float* __restrict__ bb,
    const float* __restrict__ rw, const float* __restrict__ rb,
    const float* __restrict__ w1, const float* __restrict__ b1,
    float* __restrict__ tokc, float* __restrict__ maskf,
    float* __restrict__ hid) {
  const int b = blockIdx.x;
  const int tid = threadIdx.x, w = tid >> 6, lane = tid & 63;
  __shared__ float aos[DMODEL];
  __shared__ float xd_s[DMODEL];
  __shared__ float red[8];
  __shared__ float lg[4];
  __shared__ float mk[4];
  __shared__ int epair[2];

  if (tid < 256) aos[tid] = aocf[b * DMODEL + tid];
  __syncthreads();

  float t_ = 0.f;
  if (tid < 256) {
    float val = ob[tid];
    #pragma unroll 4
    for (int i = 0; i < 64; ++i) {
      float4 wv2 = *(const float4*)(ow + (size_t)tid * DMODEL + i * 4);
      val = fmaf(wv2.x, aos[i * 4 + 0], val);
      val = fmaf(wv2.y, aos[i * 4 + 1], val);
      val = fmaf(wv2.z, aos[i * 4 + 2], val);
      val = fmaf(wv2.w, aos[i * 4 + 3], val);
    }
    t_ = cls[tid] + val;
    tokc[b * DMODEL + tid] = t_;
  }
  float s1 = warp_sum(t_), s2 = warp_sum(t_ * t_);
  if (tid < 256 && lane == 0) { red[w] = s1; red[4 + w] = s2; }
  __syncthreads();
  s1 = red[0] + red[1] + red[2] + red[3];
  s2 = red[4] + red[5] + red[6] + red[7];
  float mu = s1 * (1.f / DMODEL);
  float var = s2 * (1.f / DMODEL) - mu * mu;
  float rs = rsqrtf(var + 1e-5f);
  if (tid < 256) xd_s[tid] = (t_ - mu) * rs * g[tid] + bb[tid];
  __syncthreads();

  if (tid < 256) {
    float s = 0.f;
    #pragma unroll
    for (int i = 0; i < 4; ++i)
      s = fmaf(xd_s[lane + i * 64], rw[w * DMODEL + lane + i * 64], s);
    s = warp_sum(s) + rb[w];
    if (lane == 0) lg[w] = s;
  }
  __syncthreads();
  if (tid < NEXP) {
    int e = tid;
    int rank = 0;
    #pragma unroll
    for (int j = 0; j < NEXP; ++j)
      if (j != e && (lg[j] > lg[e] || (lg[j] == lg[e] && j < e))) ++rank;
    float m = (rank < 2) ? 1.f : 0.f;
    mk[e] = m;
    maskf[b * NEXP + e] = m;
  }
  __syncthreads();
  if (tid == 0) {
    int e0 = 0;
    while (e0 < 3 && mk[e0] == 0.f) ++e0;
    int e1 = e0 + 1;
    while (e1 < 3 && mk[e1] == 0.f) ++e1;
    epair[0] = e0; epair[1] = e1;
  }
  __syncthreads();

  const int e0 = epair[0], e1 = epair[1];
  const float* w1a = w1 + (size_t)e0 * DMODEL * FFD + tid;
  const float* w1b = w1 + (size_t)e1 * DMODEL * FFD + tid;
  float a0 = 0.f, a1 = 0.f, a2 = 0.f, a3 = 0.f;
  #pragma unroll 4
  for (int k = 0; k < DMODEL; ++k) {
    float xv = xd_s[k];
    const float* ra = w1a + (size_t)k * FFD;
    const float* rb2 = w1b + (size_t)k * FFD;
    a0 = fmaf(xv, ra[0], a0);
    a1 = fmaf(xv, ra[512], a1);
    a2 = fmaf(xv, rb2[0], a2);
    a3 = fmaf(xv, rb2[512], a3);
  }
  float* h0 = hid + ((size_t)e0 * NBATCH + b) * FFD;
  float* h1 = hid + ((size_t)e1 * NBATCH + b) * FFD;
  float v0 = a0 + b1[e0 * FFD + tid];
  float v1 = a1 + b1[e0 * FFD + tid + 512];
  float v2 = a2 + b1[e1 * FFD + tid];
  float v3 = a3 + b1[e1 * FFD + tid + 512];
  h0[tid]       = 0.5f * v0 * (1.0f + erff(v0 * 0.70710678118654752f));
  h0[tid + 512] = 0.5f * v1 * (1.0f + erff(v1 * 0.70710678118654752f));
  h1[tid]       = 0.5f * v2 * (1.0f + erff(v2 * 0.70710678118654752f));
  h1[tid + 512] = 0.5f * v3 * (1.0f + erff(v3 * 0.70710678118654752f));
}

// ---------------- MoE GEMM2 (parallel): block per (token, dchunk) ------------
__global__ __launch_bounds__(256) void k_moe2(const float* __restrict__ hid,
                                              const float* __restrict__ w2,
                                              const float* __restrict__ b2,
                                              const float* __restrict__ maskf,
                                              float* __restrict__ tokc) {
  const int t = blockIdx.x, dc = blockIdx.y;
  const int tid = threadIdx.x;
  const int dl = tid & 127, kh = tid >> 7;
  const int dout = dc * 128 + dl;
  int e0 = 0;
  while (e0 < 3 && maskf[t * NEXP + e0] == 0.f) ++e0;
  int e1 = e0 + 1;
  while (e1 < 3 && maskf[t * NEXP + e1] == 0.f) ++e1;
  __shared__ float hs0[FFD], hs1[FFD];
  const float* h0 = hid + ((size_t)e0 * NBATCH + t) * FFD;
  const float* h1 = hid + ((size_t)e1 * NBATCH + t) * FFD;
  for (int i = tid * 4; i < FFD; i += 1024) {
    *(float4*)&hs0[i] = *(const float4*)&h0[i];
    *(float4*)&hs1[i] = *(const float4*)&h1[i];
  }
  __syncthreads();
  const float* w20 = w2 + (size_t)e0 * FFD * DMODEL + dout;
  const float* w21 = w2 + (size_t)e1 * FFD * DMODEL + dout;
  float a0 = 0.f, a1 = 0.f;
  const int k0 = kh * 512;
  #pragma unroll 8
  for (int k = k0; k < k0 + 512; ++k) {
    a0 = fmaf(hs0[k], w20[(size_t)k * DMODEL], a0);
    a1 = fmaf(hs1[k], w21[(size_t)k * DMODEL], a1);
  }
  __shared__ float red[256];
  red[tid] = a0 + a1;
  __syncthreads();
  if (kh == 0) {
    float full = red[dl] + red[128 + dl] +
                 b2[e0 * DMODEL + dout] + b2[e1 * DMODEL + dout];
    tokc[t * DMODEL + dout] += full;
  }
}

// ---------------- classifier head on compact tokc ----------------------------
__global__ __launch_bounds__(256) void k_head(const float* __restrict__ tokc,
                                              const float* __restrict__ hw,
                                              const float* __restrict__ hb,
                                              float* __restrict__ out) {
  int b = blockIdx.x;
  int w = threadIdx.x >> 6, lane = threadIdx.x & 63;
  const float* row = tokc + (size_t)b * DMODEL;
  for (int c = w; c < NCLS; c += 4) {
    float s = 0.f;
    for (int d = lane; d < DMODEL; d += 64) s = fmaf(row[d], hw[c * DMODEL + d], s);
    s = warp_sum(s);
    if (lane == 0) out[b * NCLS + c] = s + hb[c];
  }
}

extern "C" void kernel_launch(void* const* d_in, const int* in_sizes, int n_in,
                              void* d_out, int out_size, void* d_ws, size_t ws_size,
                              hipStream_t stream) {
  const float* x      = (const float*)d_in[0];
  const float* conv_w = (const float*)d_in[1];
  const float* conv_b = (const float*)d_in[2];
  const float* cls    = (const float*)d_in[3];
  const float* ln1g   = (const float*)d_in[4];
  const float* ln1b   = (const float*)d_in[5];
  const float* qkv_w  = (const float*)d_in[6];
  const float* qkv_b  = (const float*)d_in[7];
  const float* out_w  = (const float*)d_in[8];
  const float* out_b  = (const float*)d_in[9];
  const float* ln2g   = (const float*)d_in[10];
  const float* ln2b   = (const float*)d_in[11];
  const float* rw     = (const float*)d_in[12];
  const float* rb     = (const float*)d_in[13];
  const float* e_w1   = (const float*)d_in[14];
  const float* e_b1   = (const float*)d_in[15];
  const float* e_w2   = (const float*)d_in[16];
  const float* e_b2   = (const float*)d_in[17];
  const float* head_w = (const float*)d_in[18];
  const float* head_b = (const float*)d_in[19];
  float* out = (float*)d_out;

  char* ws = (char*)d_ws;
  size_t off = 0;
  auto alloc = [&](size_t bytes) {
    void* p = ws + off;
    off += (bytes + 255) & ~(size_t)255;
    return p;
  };
  float*  tok   = (float*)alloc((size_t)TTOK * DMODEL * 4);    // 25.8 MB
  float*  qkvf  = (float*)alloc((size_t)TTOK * 512 * 4);       // 51.6 (K|V fp32)
  u16*    cwh   = (u16*)alloc((size_t)DMODEL * CONVK * 2);
  u16*    cwl   = (u16*)alloc((size_t)DMODEL * CONVK * 2);
  u16*    qwh   = (u16*)alloc((size_t)768 * DMODEL * 2);
  u16*    qwl   = (u16*)alloc((size_t)768 * DMODEL * 2);
  float*  qf    = (float*)alloc((size_t)DMODEL * 4);
  float*  aocf  = (float*)alloc((size_t)NBATCH * DMODEL * 4);
  float*  tokc  = (float*)alloc((size_t)NBATCH * DMODEL * 4);
  float*  maskf = (float*)alloc((size_t)NBATCH * NEXP * 4);
  float*  hid   = (float*)alloc((size_t)NEXP * NBATCH * FFD * 4);  // 2 MB

  // weight splits + q_cls (block 384) + cls rows into tok (block 385)
  k_cast2b<<<386, 256, 0, stream>>>(conv_w, cwh, cwl, qkv_w, qwh, qwl,
                                    cls, ln1g, ln1b, qkv_b, qf, tok);

  // conv GEMM (proven config, 128x128, grid 392) -> tok (CMAP)
  k_conv<<<dim3(2, CM / 128), 256, 0, stream>>>(x, cwh, cwl, conv_b, tok);

  // fused LN1-stats + LN1 + K,V projection -> fp32 [TTOK][512]
  k_qkv<<<dim3(4, TTOK / 128), 256, 0, stream>>>(
      tok, ln1g, ln1b, qwh + 256 * DMODEL, qwl + 256 * DMODEL,
      qkv_b + 256, qkvf);

  // attention: 1024 blocks (b,h), high occupancy streaming
  k_attn2<<<dim3(NBATCH, NHEADS), 256, 0, stream>>>(qf, qkvf, aocf);

  // oproj + residual + LN2 + router + MoE1, one block per batch
  k_tail2<<<NBATCH, 512, 0, stream>>>(aocf, out_w, out_b, cls,
                                      ln2g, ln2b, rw, rb,
                                      e_w1, e_b1, tokc, maskf, hid);

  // MoE GEMM2 (proven parallel config) + head
  k_moe2<<<dim3(NBATCH, 2), 256, 0, stream>>>(hid, e_w2, e_b2, maskf, tokc);
  k_head<<<NBATCH, 256, 0, stream>>>(tokc, head_w, head_b, out);
}

// Round 21
// 190.003 us; speedup vs baseline: 1.0896x; 1.0896x over previous
//
#include <hip/hip_runtime.h>
#include <hip/hip_bf16.h>
#include <math.h>

#define TTOK   25216      // 128*197
#define SEQL   197
#define NBATCH 128
#define DMODEL 256
#define NHEADS 8
#define FFD    1024
#define NEXP   4
#define NCLS   38
#define CONVK  768
#define NPATCH 196
#define CM     25088      // conv GEMM rows = 128*196

typedef unsigned short u16;
typedef unsigned int u32;
using s16x4 = __attribute__((ext_vector_type(4))) short;
using s16x8 = __attribute__((ext_vector_type(8))) short;
using f32x4 = __attribute__((ext_vector_type(4))) float;

__device__ __forceinline__ float b2f(u16 v) {
  union { unsigned u; float f; } x; x.u = (unsigned)v << 16; return x.f;
}
__device__ __forceinline__ u16 f2b(float f) {
  __hip_bfloat16 h = __float2bfloat16(f);
  return *reinterpret_cast<u16*>(&h);
}
__device__ __forceinline__ void gload16(const void* g, void* l) {
  __builtin_amdgcn_global_load_lds(
      (const __attribute__((address_space(1))) void*)g,
      (__attribute__((address_space(3))) void*)l, 16, 0, 0);
}
__device__ __forceinline__ float warp_sum(float v) {
  #pragma unroll
  for (int o = 32; o; o >>= 1) v += __shfl_xor(v, o);
  return v;
}
__device__ __forceinline__ float warp_max(float v) {
  #pragma unroll
  for (int o = 32; o; o >>= 1) v = fmaxf(v, __shfl_xor(v, o));
  return v;
}
__device__ __forceinline__ int fsw(int row) { return (row ^ (row >> 2)) & 3; }
__device__ __forceinline__ s16x8 ldA72(const u16* base, int rowa, int l4) {
  const char* p = (const char*)base + rowa * 72 + l4 * 16;
  s16x4 a = *(const s16x4*)p;
  s16x4 b = *(const s16x4*)(p + 8);
  return __builtin_shufflevector(a, b, 0, 1, 2, 3, 4, 5, 6, 7);
}

// ---------------- weight splits (384 blocks) + q_cls (block 384) -------------
__global__ __launch_bounds__(256) void k_cast2b(const float* __restrict__ cw,
                                                u16* __restrict__ cwh,
                                                u16* __restrict__ cwl,
                                                const float* __restrict__ qw,
                                                u16* __restrict__ qwh,
                                                u16* __restrict__ qwl,
                                                const float* __restrict__ cls,
                                                const float* __restrict__ ln1g,
                                                const float* __restrict__ ln1b,
                                                const float* __restrict__ qb,
                                                float* __restrict__ qf) {
  int bid = blockIdx.x;
  if (bid == 384) {
    const int n = threadIdx.x, w = n >> 6, lane = n & 63;
    __shared__ float xs[DMODEL];
    __shared__ float red[8];
    float v = cls[n];
    float s1 = warp_sum(v), s2 = warp_sum(v * v);
    if (lane == 0) { red[w] = s1; red[4 + w] = s2; }
    __syncthreads();
    s1 = red[0] + red[1] + red[2] + red[3];
    s2 = red[4] + red[5] + red[6] + red[7];
    float mu = s1 * (1.f / DMODEL);
    float var = s2 * (1.f / DMODEL) - mu * mu;
    float rs = rsqrtf(var + 1e-5f);
    xs[n] = (v - mu) * rs * ln1g[n] + ln1b[n];
    __syncthreads();
    float val = qb[n];
    #pragma unroll 4
    for (int i = 0; i < 64; ++i) {
      float4 wv = *(const float4*)(qw + (size_t)n * DMODEL + i * 4);
      val = fmaf(wv.x, xs[i * 4 + 0], val);
      val = fmaf(wv.y, xs[i * 4 + 1], val);
      val = fmaf(wv.z, xs[i * 4 + 2], val);
      val = fmaf(wv.w, xs[i * 4 + 3], val);
    }
    qf[n] = val;
    return;
  }
  const float* in = cw; u16* hi = cwh; u16* lo = cwl;
  if (bid >= 192) { bid -= 192; in = qw; hi = qwh; lo = qwl; }
  int i = (bid * 256 + threadIdx.x) * 4;
  float4 v = *(const float4*)&in[i];
  float vv[4] = {v.x, v.y, v.z, v.w};
  u16 h[4], l[4];
  #pragma unroll
  for (int j = 0; j < 4; ++j) {
    h[j] = f2b(vv[j]);
    l[j] = f2b(vv[j] - b2f(h[j]));
  }
  *(uint2*)&hi[i] = *(const uint2*)h;
  *(uint2*)&lo[i] = *(const uint2*)l;
}

// ---------------- fused im2col + split-MFMA conv GEMM, tile 128x128 ----------
__global__ __launch_bounds__(256) void k_conv(const float* __restrict__ x,
                                              const u16* __restrict__ cwh,
                                              const u16* __restrict__ cwl,
                                              const float* __restrict__ cb,
                                              float* __restrict__ tok) {
  const int n0 = blockIdx.x * 128;
  const int m0 = blockIdx.y * 128;
  __shared__ __align__(16) u16 lds[25600];   // A h/l (2*4608) + W dbuf (16384)
  u16* Ah_s = lds;
  u16* Al_s = lds + 4608;
  u16* Wbuf = lds + 9216;
  const int tid = threadIdx.x;
  const int lane = tid & 63;
  const int wv = tid >> 6;
  const int wr = wv >> 1, wc = wv & 1;
  const int l15 = lane & 15, l4 = lane >> 4;
  f32x4 acc[4][4] = {};

  const int kpos = (tid & 7) * 4;
  long abase[4]; int aldso[4];
  #pragma unroll
  for (int it = 0; it < 4; ++it) {
    int row = it * 32 + (tid >> 3);
    int m = m0 + row;
    int b = m / NPATCH, p = m - b * NPATCH;
    int py = p / 14, px = p - py * 14;
    abase[it] = (long)(b * 3) * 50176 + (py * 16) * 224 + px * 16;
    aldso[it] = row * 72 + kpos * 2;
  }
  long woff[2]; int wofs[2];
  #pragma unroll
  for (int r = 0; r < 2; ++r) {
    int off = r * 4096 + tid * 16;
    int row = off >> 6;
    int c16 = (off >> 4) & 3;
    int kk = (c16 ^ fsw(row)) << 3;
    woff[r] = (long)(n0 + row) * CONVK + kk;
    wofs[r] = off;
  }
  #pragma unroll
  for (int r = 0; r < 2; ++r) {
    gload16(cwh + woff[r], (char*)Wbuf + wofs[r]);
    gload16(cwl + woff[r], (char*)Wbuf + 8192 + wofs[r]);
  }
  float4 xr[4];
  {
    int c = kpos >> 8, r8 = kpos & 255;
    long soff = (long)c * 50176 + (r8 >> 4) * 224 + (r8 & 15);
    #pragma unroll
    for (int it = 0; it < 4; ++it) xr[it] = *(const float4*)&x[abase[it] + soff];
  }
  int cur = 0;
  for (int kc = 0; kc < CONVK; kc += 32) {
    #pragma unroll
    for (int it = 0; it < 4; ++it) {
      float vv[4] = {xr[it].x, xr[it].y, xr[it].z, xr[it].w};
      u16 h[4], l[4];
      #pragma unroll
      for (int j = 0; j < 4; ++j) {
        h[j] = f2b(vv[j]);
        l[j] = f2b(vv[j] - b2f(h[j]));
      }
      *(uint2*)((char*)Ah_s + aldso[it]) = *(const uint2*)h;
      *(uint2*)((char*)Al_s + aldso[it]) = *(const uint2*)l;
    }
    __syncthreads();                         // bar1 (ds_write visible)
    if (kc + 32 < CONVK) {                   // prefetch next W + x under MFMA
      char* wdst = (char*)Wbuf + ((cur ^ 1) << 14);
      #pragma unroll
      for (int r = 0; r < 2; ++r) {
        gload16(cwh + woff[r] + kc + 32, wdst + wofs[r]);
        gload16(cwl + woff[r] + kc + 32, wdst + 8192 + wofs[r]);
      }
      int k = kc + 32 + kpos;
      int c = k >> 8, r8 = k & 255;
      long soff = (long)c * 50176 + (r8 >> 4) * 224 + (r8 & 15);
      #pragma unroll
      for (int it = 0; it < 4; ++it) xr[it] = *(const float4*)&x[abase[it] + soff];
    }
    const char* Wcur = (const char*)Wbuf + (cur << 14);
    s16x8 ah[4], al[4], bh[4], bl[4];
    #pragma unroll
    for (int i = 0; i < 4; ++i) {
      int rowa = wr * 64 + i * 16 + l15;
      ah[i] = ldA72(Ah_s, rowa, l4);
      al[i] = ldA72(Al_s, rowa, l4);
      int rowb = wc * 64 + i * 16 + l15;
      int kbb = (l4 ^ fsw(rowb)) << 4;
      bh[i] = *(const s16x8*)(Wcur + rowb * 64 + kbb);
      bl[i] = *(const s16x8*)(Wcur + 8192 + rowb * 64 + kbb);
    }
    #pragma unroll
    for (int i = 0; i < 4; ++i)
      #pragma unroll
      for (int j = 0; j < 4; ++j)
        acc[i][j] = __builtin_amdgcn_mfma_f32_16x16x32_bf16(ah[i], bh[j],
                                                            acc[i][j], 0, 0, 0);
    #pragma unroll
    for (int i = 0; i < 4; ++i)
      #pragma unroll
      for (int j = 0; j < 4; ++j)
        acc[i][j] = __builtin_amdgcn_mfma_f32_16x16x32_bf16(ah[i], bl[j],
                                                            acc[i][j], 0, 0, 0);
    #pragma unroll
    for (int i = 0; i < 4; ++i)
      #pragma unroll
      for (int j = 0; j < 4; ++j)
        acc[i][j] = __builtin_amdgcn_mfma_f32_16x16x32_bf16(al[i], bh[j],
                                                            acc[i][j], 0, 0, 0);
    __syncthreads();                         // bar2 (drains prefetch under MFMA)
    cur ^= 1;
  }
  const int mb = m0 + wr * 64 + (l4 << 2);
  const int nb = n0 + wc * 64 + l15;
  #pragma unroll
  for (int i = 0; i < 4; ++i) {
    #pragma unroll
    for (int jf = 0; jf < 4; ++jf) {
      #pragma unroll
      for (int j = 0; j < 4; ++j) {
        int m = mb + i * 16 + j;
        int n = nb + jf * 16;
        int bq = m / NPATCH;
        long cr = (long)bq * SEQL + (m - bq * NPATCH) + 1;
        tok[cr * DMODEL + n] = acc[i][jf][j] + cb[n];
      }
    }
  }
}

// ---------------- LN1 stats for all rows; writes cls rows into tok -----------
__global__ __launch_bounds__(256) void k_lnstat(const float* __restrict__ cls,
                                                float* __restrict__ tok,
                                                float2* __restrict__ st) {
  const int row = blockIdx.x * 4 + (threadIdx.x >> 6);
  const int lane = threadIdx.x & 63;
  const int b = row / SEQL, s = row - b * SEQL;
  float vv[4];
  if (s == 0) {
    *(float4*)vv = *(const float4*)&cls[lane * 4];
    *(float4*)&tok[(size_t)row * DMODEL + lane * 4] = *(const float4*)vv;
  } else {
    *(float4*)vv = *(const float4*)&tok[(size_t)row * DMODEL + lane * 4];
  }
  float s1 = vv[0] + vv[1] + vv[2] + vv[3];
  float s2 = vv[0]*vv[0] + vv[1]*vv[1] + vv[2]*vv[2] + vv[3]*vv[3];
  s1 = warp_sum(s1);
  s2 = warp_sum(s2);
  if (lane == 0) {
    float mu = s1 * (1.f / DMODEL);
    float var = s2 * (1.f / DMODEL) - mu * mu;
    st[row] = make_float2(mu, rsqrtf(var + 1e-5f));
  }
}

// ---------------- fused LN1 + K/V split-MFMA GEMM, tile 128x128 --------------
__global__ __launch_bounds__(256) void k_qkv(const float* __restrict__ tok,
                                             const float2* __restrict__ stats,
                                             const float* __restrict__ g,
                                             const float* __restrict__ bb,
                                             const u16* __restrict__ Wh,
                                             const u16* __restrict__ Wl,
                                             const float* __restrict__ bias,
                                             float* __restrict__ Cf) {
  const int n0 = blockIdx.x * 128;
  const int m0 = blockIdx.y * 128;
  __shared__ __align__(16) u16 lds[25600];
  u16* Ah_s = lds;
  u16* Al_s = lds + 4608;
  u16* Wbuf = lds + 9216;
  const int tid = threadIdx.x;
  const int lane = tid & 63;
  const int wv = tid >> 6;
  const int wr = wv >> 1, wc = wv & 1;
  const int l15 = lane & 15, l4 = lane >> 4;
  f32x4 acc[4][4] = {};

  const int kpos = (tid & 7) * 4;
  long atok[4]; float2 st[4]; int aldso[4];
  #pragma unroll
  for (int it = 0; it < 4; ++it) {
    int row = it * 32 + (tid >> 3);
    int m = m0 + row;
    atok[it] = (long)m * DMODEL;
    st[it] = stats[m];
    aldso[it] = row * 72 + kpos * 2;
  }
  long woff[2]; int wofs[2];
  #pragma unroll
  for (int r = 0; r < 2; ++r) {
    int off = r * 4096 + tid * 16;
    int row = off >> 6;
    int c16 = (off >> 4) & 3;
    int kk = (c16 ^ fsw(row)) << 3;
    woff[r] = (long)(n0 + row) * DMODEL + kk;
    wofs[r] = off;
  }
  #pragma unroll
  for (int r = 0; r < 2; ++r) {
    gload16(Wh + woff[r], (char*)Wbuf + wofs[r]);
    gload16(Wl + woff[r], (char*)Wbuf + 8192 + wofs[r]);
  }
  float4 xr[4], gr, br;
  #pragma unroll
  for (int it = 0; it < 4; ++it) xr[it] = *(const float4*)&tok[atok[it] + kpos];
  gr = *(const float4*)&g[kpos];
  br = *(const float4*)&bb[kpos];
  int cur = 0;
  for (int kc = 0; kc < DMODEL; kc += 32) {
    float gg[4] = {gr.x, gr.y, gr.z, gr.w};
    float bbv[4] = {br.x, br.y, br.z, br.w};
    #pragma unroll
    for (int it = 0; it < 4; ++it) {
      float vv[4] = {xr[it].x, xr[it].y, xr[it].z, xr[it].w};
      u16 h[4], l[4];
      #pragma unroll
      for (int j = 0; j < 4; ++j) {
        float xd = (vv[j] - st[it].x) * st[it].y * gg[j] + bbv[j];
        h[j] = f2b(xd);
        l[j] = f2b(xd - b2f(h[j]));
      }
      *(uint2*)((char*)Ah_s + aldso[it]) = *(const uint2*)h;
      *(uint2*)((char*)Al_s + aldso[it]) = *(const uint2*)l;
    }
    __syncthreads();
    if (kc + 32 < DMODEL) {
      char* wdst = (char*)Wbuf + ((cur ^ 1) << 14);
      #pragma unroll
      for (int r = 0; r < 2; ++r) {
        gload16(Wh + woff[r] + kc + 32, wdst + wofs[r]);
        gload16(Wl + woff[r] + kc + 32, wdst + 8192 + wofs[r]);
      }
      #pragma unroll
      for (int it = 0; it < 4; ++it)
        xr[it] = *(const float4*)&tok[atok[it] + kc + 32 + kpos];
      gr = *(const float4*)&g[kc + 32 + kpos];
      br = *(const float4*)&bb[kc + 32 + kpos];
    }
    const char* Wcur = (const char*)Wbuf + (cur << 14);
    s16x8 ah[4], al[4], bh[4], bl[4];
    #pragma unroll
    for (int i = 0; i < 4; ++i) {
      int rowa = wr * 64 + i * 16 + l15;
      ah[i] = ldA72(Ah_s, rowa, l4);
      al[i] = ldA72(Al_s, rowa, l4);
      int rowb = wc * 64 + i * 16 + l15;
      int kbb = (l4 ^ fsw(rowb)) << 4;
      bh[i] = *(const s16x8*)(Wcur + rowb * 64 + kbb);
      bl[i] = *(const s16x8*)(Wcur + 8192 + rowb * 64 + kbb);
    }
    #pragma unroll
    for (int i = 0; i < 4; ++i)
      #pragma unroll
      for (int j = 0; j < 4; ++j)
        acc[i][j] = __builtin_amdgcn_mfma_f32_16x16x32_bf16(ah[i], bh[j],
                                                            acc[i][j], 0, 0, 0);
    #pragma unroll
    for (int i = 0; i < 4; ++i)
      #pragma unroll
      for (int j = 0; j < 4; ++j)
        acc[i][j] = __builtin_amdgcn_mfma_f32_16x16x32_bf16(ah[i], bl[j],
                                                            acc[i][j], 0, 0, 0);
    #pragma unroll
    for (int i = 0; i < 4; ++i)
      #pragma unroll
      for (int j = 0; j < 4; ++j)
        acc[i][j] = __builtin_amdgcn_mfma_f32_16x16x32_bf16(al[i], bh[j],
                                                            acc[i][j], 0, 0, 0);
    __syncthreads();
    cur ^= 1;
  }
  const int mb = m0 + wr * 64 + (l4 << 2);
  const int nb = n0 + wc * 64 + l15;
  #pragma unroll
  for (int i = 0; i < 4; ++i) {
    #pragma unroll
    for (int jf = 0; jf < 4; ++jf) {
      #pragma unroll
      for (int j = 0; j < 4; ++j) {
        int m = mb + i * 16 + j;
        int n = nb + jf * 16;
        Cf[(long)m * 512 + n] = acc[i][jf][j] + bias[n];
      }
    }
  }
}

// ---------------- attention v3: one block per (b,h), 256 thr -----------------
__global__ __launch_bounds__(256) void k_attn2(const float* __restrict__ qf,
                                               const float* __restrict__ kvf,
                                               float* __restrict__ aocf) {
  const int b = blockIdx.x, h = blockIdx.y;
  const int tid = threadIdx.x, w = tid >> 6, lane = tid & 63;
  __shared__ float qs[32];
  __shared__ float Ps[256];
  __shared__ float red[8];
  __shared__ float pvred[8][32];
  if (tid < 32) qs[tid] = qf[h * 32 + tid];
  __syncthreads();
  float s = -1e30f;
  if (tid < SEQL) {
    const float* kr = kvf + ((size_t)(b * SEQL + tid)) * 512 + h * 32;
    float a = 0.f;
    #pragma unroll
    for (int i = 0; i < 8; ++i) {
      float4 k4 = *(const float4*)(kr + i * 4);
      a = fmaf(k4.x, qs[i * 4 + 0], a);
      a = fmaf(k4.y, qs[i * 4 + 1], a);
      a = fmaf(k4.z, qs[i * 4 + 2], a);
      a = fmaf(k4.w, qs[i * 4 + 3], a);
    }
    s = a * 0.17677669529663687f;  // 1/sqrt(32)
  }
  float mx = warp_max(s);
  if (lane == 0) red[w] = mx;
  __syncthreads();
  mx = fmaxf(fmaxf(red[0], red[1]), fmaxf(red[2], red[3]));
  float e = (tid < SEQL) ? __expf(s - mx) : 0.f;
  float ssum = warp_sum(e);
  if (lane == 0) red[4 + w] = ssum;
  __syncthreads();
  float inv = 1.f / (red[4] + red[5] + red[6] + red[7]);
  Ps[tid] = e * inv;
  __syncthreads();
  const int d = tid & 31, kq = tid >> 5;
  float acc = 0.f;
  const int kbeg = kq * 25;
  #pragma unroll 5
  for (int i = 0; i < 25; ++i) {
    int k = kbeg + i;
    if (k < SEQL)
      acc = fmaf(Ps[k], kvf[((size_t)(b * SEQL + k)) * 512 + 256 + h * 32 + d], acc);
  }
  pvred[kq][d] = acc;
  __syncthreads();
  if (tid < 32) {
    float r = 0.f;
    #pragma unroll
    for (int j = 0; j < 8; ++j) r += pvred[j][tid];
    aocf[b * DMODEL + h * 32 + tid] = r;
  }
}

// ---------------- fused oproj + residual(cls) + LN2 + router + MoE1 ----------
__global__ __launch_bounds__(512) void k_tail2(
    const float* __restrict__ aocf,
    const float* __restrict__ ow, const float* __restrict__ ob,
    const float* __restrict__ cls,
    const float* __restrict__ g, const float* __restrict__ bb,
    const float* __restrict__ rw, const float* __restrict__ rb,
    const float* __restrict__ w1, const float* __restrict__ b1,
    float* __restrict__ tokc, float* __restrict__ maskf,
    float* __restrict__ hid) {
  const int b = blockIdx.x;
  const int tid = threadIdx.x, w = tid >> 6, lane = tid & 63;
  __shared__ float aos[DMODEL];
  __shared__ float xd_s[DMODEL];
  __shared__ float red[8];
  __shared__ float lg[4];
  __shared__ float mk[4];
  __shared__ int epair[2];

  if (tid < 256) aos[tid] = aocf[b * DMODEL + tid];
  __syncthreads();

  float t_ = 0.f;
  if (tid < 256) {
    float val = ob[tid];
    #pragma unroll 4
    for (int i = 0; i < 64; ++i) {
      float4 wv2 = *(const float4*)(ow + (size_t)tid * DMODEL + i * 4);
      val = fmaf(wv2.x, aos[i * 4 + 0], val);
      val = fmaf(wv2.y, aos[i * 4 + 1], val);
      val = fmaf(wv2.z, aos[i * 4 + 2], val);
      val = fmaf(wv2.w, aos[i * 4 + 3], val);
    }
    t_ = cls[tid] + val;
    tokc[b * DMODEL + tid] = t_;
  }
  float s1 = warp_sum(t_), s2 = warp_sum(t_ * t_);
  if (tid < 256 && lane == 0) { red[w] = s1; red[4 + w] = s2; }
  __syncthreads();
  s1 = red[0] + red[1] + red[2] + red[3];
  s2 = red[4] + red[5] + red[6] + red[7];
  float mu = s1 * (1.f / DMODEL);
  float var = s2 * (1.f / DMODEL) - mu * mu;
  float rs = rsqrtf(var + 1e-5f);
  if (tid < 256) xd_s[tid] = (t_ - mu) * rs * g[tid] + bb[tid];
  __syncthreads();

  if (tid < 256) {
    float s = 0.f;
    #pragma unroll
    for (int i = 0; i < 4; ++i)
      s = fmaf(xd_s[lane + i * 64], rw[w * DMODEL + lane + i * 64], s);
    s = warp_sum(s) + rb[w];
    if (lane == 0) lg[w] = s;
  }
  __syncthreads();
  if (tid < NEXP) {
    int e = tid;
    int rank = 0;
    #pragma unroll
    for (int j = 0; j < NEXP; ++j)
      if (j != e && (lg[j] > lg[e] || (lg[j] == lg[e] && j < e))) ++rank;
    float m = (rank < 2) ? 1.f : 0.f;
    mk[e] = m;
    maskf[b * NEXP + e] = m;
  }
  __syncthreads();
  if (tid == 0) {
    int e0 = 0;
    while (e0 < 3 && mk[e0] == 0.f) ++e0;
    int e1 = e0 + 1;
    while (e1 < 3 && mk[e1] == 0.f) ++e1;
    epair[0] = e0; epair[1] = e1;
  }
  __syncthreads();

  const int e0 = epair[0], e1 = epair[1];
  const float* w1a = w1 + (size_t)e0 * DMODEL * FFD + tid;
  const float* w1b = w1 + (size_t)e1 * DMODEL * FFD + tid;
  float a0 = 0.f, a1 = 0.f, a2 = 0.f, a3 = 0.f;
  #pragma unroll 4
  for (int k = 0; k < DMODEL; ++k) {
    float xv = xd_s[k];
    const float* ra = w1a + (size_t)k * FFD;
    const float* rb2 = w1b + (size_t)k * FFD;
    a0 = fmaf(xv, ra[0], a0);
    a1 = fmaf(xv, ra[512], a1);
    a2 = fmaf(xv, rb2[0], a2);
    a3 = fmaf(xv, rb2[512], a3);
  }
  float* h0 = hid + ((size_t)e0 * NBATCH + b) * FFD;
  float* h1 = hid + ((size_t)e1 * NBATCH + b) * FFD;
  float v0 = a0 + b1[e0 * FFD + tid];
  float v1 = a1 + b1[e0 * FFD + tid + 512];
  float v2 = a2 + b1[e1 * FFD + tid];
  float v3 = a3 + b1[e1 * FFD + tid + 512];
  h0[tid]       = 0.5f * v0 * (1.0f + erff(v0 * 0.70710678118654752f));
  h0[tid + 512] = 0.5f * v1 * (1.0f + erff(v1 * 0.70710678118654752f));
  h1[tid]       = 0.5f * v2 * (1.0f + erff(v2 * 0.70710678118654752f));
  h1[tid + 512] = 0.5f * v3 * (1.0f + erff(v3 * 0.70710678118654752f));
}

// ---------------- MoE GEMM2 (parallel): block per (token, dchunk) ------------
__global__ __launch_bounds__(256) void k_moe2(const float* __restrict__ hid,
                                              const float* __restrict__ w2,
                                              const float* __restrict__ b2,
                                              const float* __restrict__ maskf,
                                              float* __restrict__ tokc) {
  const int t = blockIdx.x, dc = blockIdx.y;
  const int tid = threadIdx.x;
  const int dl = tid & 127, kh = tid >> 7;
  const int dout = dc * 128 + dl;
  int e0 = 0;
  while (e0 < 3 && maskf[t * NEXP + e0] == 0.f) ++e0;
  int e1 = e0 + 1;
  while (e1 < 3 && maskf[t * NEXP + e1] == 0.f) ++e1;
  __shared__ float hs0[FFD], hs1[FFD];
  const float* h0 = hid + ((size_t)e0 * NBATCH + t) * FFD;
  const float* h1 = hid + ((size_t)e1 * NBATCH + t) * FFD;
  for (int i = tid * 4; i < FFD; i += 1024) {
    *(float4*)&hs0[i] = *(const float4*)&h0[i];
    *(float4*)&hs1[i] = *(const float4*)&h1[i];
  }
  __syncthreads();
  const float* w20 = w2 + (size_t)e0 * FFD * DMODEL + dout;
  const float* w21 = w2 + (size_t)e1 * FFD * DMODEL + dout;
  float a0 = 0.f, a1 = 0.f;
  const int k0 = kh * 512;
  #pragma unroll 8
  for (int k = k0; k < k0 + 512; ++k) {
    a0 = fmaf(hs0[k], w20[(size_t)k * DMODEL], a0);
    a1 = fmaf(hs1[k], w21[(size_t)k * DMODEL], a1);
  }
  __shared__ float red[256];
  red[tid] = a0 + a1;
  __syncthreads();
  if (kh == 0) {
    float full = red[dl] + red[128 + dl] +
                 b2[e0 * DMODEL + dout] + b2[e1 * DMODEL + dout];
    tokc[t * DMODEL + dout] += full;
  }
}

// ---------------- classifier head on compact tokc ----------------------------
__global__ __launch_bounds__(256) void k_head(const float* __restrict__ tokc,
                                              const float* __restrict__ hw,
                                              const float* __restrict__ hb,
                                              float* __restrict__ out) {
  int b = blockIdx.x;
  int w = threadIdx.x >> 6, lane = threadIdx.x & 63;
  const float* row = tokc + (size_t)b * DMODEL;
  for (int c = w; c < NCLS; c += 4) {
    float s = 0.f;
    for (int d = lane; d < DMODEL; d += 64) s = fmaf(row[d], hw[c * DMODEL + d], s);
    s = warp_sum(s);
    if (lane == 0) out[b * NCLS + c] = s + hb[c];
  }
}

extern "C" void kernel_launch(void* const* d_in, const int* in_sizes, int n_in,
                              void* d_out, int out_size, void* d_ws, size_t ws_size,
                              hipStream_t stream) {
  const float* x      = (const float*)d_in[0];
  const float* conv_w = (const float*)d_in[1];
  const float* conv_b = (const float*)d_in[2];
  const float* cls    = (const float*)d_in[3];
  const float* ln1g   = (const float*)d_in[4];
  const float* ln1b   = (const float*)d_in[5];
  const float* qkv_w  = (const float*)d_in[6];
  const float* qkv_b  = (const float*)d_in[7];
  const float* out_w  = (const float*)d_in[8];
  const float* out_b  = (const float*)d_in[9];
  const float* ln2g   = (const float*)d_in[10];
  const float* ln2b   = (const float*)d_in[11];
  const float* rw     = (const float*)d_in[12];
  const float* rb     = (const float*)d_in[13];
  const float* e_w1   = (const float*)d_in[14];
  const float* e_b1   = (const float*)d_in[15];
  const float* e_w2   = (const float*)d_in[16];
  const float* e_b2   = (const float*)d_in[17];
  const float* head_w = (const float*)d_in[18];
  const float* head_b = (const float*)d_in[19];
  float* out = (float*)d_out;

  char* ws = (char*)d_ws;
  size_t off = 0;
  auto alloc = [&](size_t bytes) {
    void* p = ws + off;
    off += (bytes + 255) & ~(size_t)255;
    return p;
  };
  float*  tok   = (float*)alloc((size_t)TTOK * DMODEL * 4);    // 25.8 MB
  float*  qkvf  = (float*)alloc((size_t)TTOK * 512 * 4);       // 51.6 (K|V fp32)
  float2* stats = (float2*)alloc((size_t)TTOK * 8);            // 0.2
  u16*    cwh   = (u16*)alloc((size_t)DMODEL * CONVK * 2);
  u16*    cwl   = (u16*)alloc((size_t)DMODEL * CONVK * 2);
  u16*    qwh   = (u16*)alloc((size_t)768 * DMODEL * 2);
  u16*    qwl   = (u16*)alloc((size_t)768 * DMODEL * 2);
  float*  qf    = (float*)alloc((size_t)DMODEL * 4);
  float*  aocf  = (float*)alloc((size_t)NBATCH * DMODEL * 4);
  float*  tokc  = (float*)alloc((size_t)NBATCH * DMODEL * 4);
  float*  maskf = (float*)alloc((size_t)NBATCH * NEXP * 4);
  float*  hid   = (float*)alloc((size_t)NEXP * NBATCH * FFD * 4);  // 2 MB

  // weight splits + q_cls (block 384)
  k_cast2b<<<385, 256, 0, stream>>>(conv_w, cwh, cwl, qkv_w, qwh, qwl,
                                    cls, ln1g, ln1b, qkv_b, qf);

  // conv GEMM (proven config, 128x128, grid 392) -> tok (CMAP)
  k_conv<<<dim3(2, CM / 128), 256, 0, stream>>>(x, cwh, cwl, conv_b, tok);

  // cls rows into tok + LN1 stats for all rows
  k_lnstat<<<TTOK / 4, 256, 0, stream>>>(cls, tok, stats);

  // fused LN1 + K,V projection (proven config) -> fp32 [TTOK][512]
  k_qkv<<<dim3(4, TTOK / 128), 256, 0, stream>>>(
      tok, stats, ln1g, ln1b, qwh + 256 * DMODEL, qwl + 256 * DMODEL,
      qkv_b + 256, qkvf);

  // attention: 1024 blocks (b,h), high occupancy streaming
  k_attn2<<<dim3(NBATCH, NHEADS), 256, 0, stream>>>(qf, qkvf, aocf);

  // oproj + residual + LN2 + router + MoE1, one block per batch
  k_tail2<<<NBATCH, 512, 0, stream>>>(aocf, out_w, out_b, cls,
                                      ln2g, ln2b, rw, rb,
                                      e_w1, e_b1, tokc, maskf, hid);

  // MoE GEMM2 (proven parallel config) + head
  k_moe2<<<dim3(NBATCH, 2), 256, 0, stream>>>(hid, e_w2, e_b2, maskf, tokc);
  k_head<<<NBATCH, 256, 0, stream>>>(tokc, head_w, head_b, out);
}

// Round 22
// 187.442 us; speedup vs baseline: 1.1045x; 1.0137x over previous
//
#include <hip/hip_runtime.h>
#include <hip/hip_bf16.h>
#include <math.h>

#define TTOK   25216      // 128*197
#define SEQL   197
#define NBATCH 128
#define DMODEL 256
#define NHEADS 8
#define FFD    1024
#define NEXP   4
#define NCLS   38
#define CONVK  768
#define NPATCH 196
#define CM     25088      // conv GEMM rows = 128*196

typedef unsigned short u16;
typedef unsigned int u32;
using s16x4 = __attribute__((ext_vector_type(4))) short;
using s16x8 = __attribute__((ext_vector_type(8))) short;
using f32x4 = __attribute__((ext_vector_type(4))) float;

__device__ __forceinline__ float b2f(u16 v) {
  union { unsigned u; float f; } x; x.u = (unsigned)v << 16; return x.f;
}
__device__ __forceinline__ u16 f2b(float f) {
  __hip_bfloat16 h = __float2bfloat16(f);
  return *reinterpret_cast<u16*>(&h);
}
__device__ __forceinline__ void gload16(const void* g, void* l) {
  __builtin_amdgcn_global_load_lds(
      (const __attribute__((address_space(1))) void*)g,
      (__attribute__((address_space(3))) void*)l, 16, 0, 0);
}
__device__ __forceinline__ float warp_sum(float v) {
  #pragma unroll
  for (int o = 32; o; o >>= 1) v += __shfl_xor(v, o);
  return v;
}
__device__ __forceinline__ float warp_max(float v) {
  #pragma unroll
  for (int o = 32; o; o >>= 1) v = fmaxf(v, __shfl_xor(v, o));
  return v;
}
__device__ __forceinline__ int fsw(int row) { return (row ^ (row >> 2)) & 3; }
__device__ __forceinline__ s16x8 ldA72(const u16* base, int rowa, int l4) {
  const char* p = (const char*)base + rowa * 72 + l4 * 16;
  s16x4 a = *(const s16x4*)p;
  s16x4 b = *(const s16x4*)(p + 8);
  return __builtin_shufflevector(a, b, 0, 1, 2, 3, 4, 5, 6, 7);
}

// ---------------- weight splits (384 blocks) + q_cls (block 384) -------------
__global__ __launch_bounds__(256) void k_cast2b(const float* __restrict__ cw,
                                                u16* __restrict__ cwh,
                                                u16* __restrict__ cwl,
                                                const float* __restrict__ qw,
                                                u16* __restrict__ qwh,
                                                u16* __restrict__ qwl,
                                                const float* __restrict__ cls,
                                                const float* __restrict__ ln1g,
                                                const float* __restrict__ ln1b,
                                                const float* __restrict__ qb,
                                                float* __restrict__ qf) {
  int bid = blockIdx.x;
  if (bid == 384) {
    const int n = threadIdx.x, w = n >> 6, lane = n & 63;
    __shared__ float xs[DMODEL];
    __shared__ float red[8];
    float v = cls[n];
    float s1 = warp_sum(v), s2 = warp_sum(v * v);
    if (lane == 0) { red[w] = s1; red[4 + w] = s2; }
    __syncthreads();
    s1 = red[0] + red[1] + red[2] + red[3];
    s2 = red[4] + red[5] + red[6] + red[7];
    float mu = s1 * (1.f / DMODEL);
    float var = s2 * (1.f / DMODEL) - mu * mu;
    float rs = rsqrtf(var + 1e-5f);
    xs[n] = (v - mu) * rs * ln1g[n] + ln1b[n];
    __syncthreads();
    float val = qb[n];
    #pragma unroll 4
    for (int i = 0; i < 64; ++i) {
      float4 wv = *(const float4*)(qw + (size_t)n * DMODEL + i * 4);
      val = fmaf(wv.x, xs[i * 4 + 0], val);
      val = fmaf(wv.y, xs[i * 4 + 1], val);
      val = fmaf(wv.z, xs[i * 4 + 2], val);
      val = fmaf(wv.w, xs[i * 4 + 3], val);
    }
    qf[n] = val;
    return;
  }
  const float* in = cw; u16* hi = cwh; u16* lo = cwl;
  if (bid >= 192) { bid -= 192; in = qw; hi = qwh; lo = qwl; }
  int i = (bid * 256 + threadIdx.x) * 4;
  float4 v = *(const float4*)&in[i];
  float vv[4] = {v.x, v.y, v.z, v.w};
  u16 h[4], l[4];
  #pragma unroll
  for (int j = 0; j < 4; ++j) {
    h[j] = f2b(vv[j]);
    l[j] = f2b(vv[j] - b2f(h[j]));
  }
  *(uint2*)&hi[i] = *(const uint2*)h;
  *(uint2*)&lo[i] = *(const uint2*)l;
}

// ---------------- fused im2col + split-MFMA conv GEMM, tile 128x128 ----------
// 1D grid 392 with XCD-aware swizzle: wid = (lin%8)*49 + lin/8 (bijective).
__global__ __launch_bounds__(256) void k_conv(const float* __restrict__ x,
                                              const u16* __restrict__ cwh,
                                              const u16* __restrict__ cwl,
                                              const float* __restrict__ cb,
                                              float* __restrict__ tok) {
  const int lin = blockIdx.x;
  const int wid = (lin & 7) * 49 + (lin >> 3);
  const int n0 = (wid & 1) * 128;
  const int m0 = (wid >> 1) * 128;
  __shared__ __align__(16) u16 lds[25600];   // A h/l (2*4608) + W dbuf (16384)
  u16* Ah_s = lds;
  u16* Al_s = lds + 4608;
  u16* Wbuf = lds + 9216;
  const int tid = threadIdx.x;
  const int lane = tid & 63;
  const int wv = tid >> 6;
  const int wr = wv >> 1, wc = wv & 1;
  const int l15 = lane & 15, l4 = lane >> 4;
  f32x4 acc[4][4] = {};

  const int kpos = (tid & 7) * 4;
  long abase[4]; int aldso[4];
  #pragma unroll
  for (int it = 0; it < 4; ++it) {
    int row = it * 32 + (tid >> 3);
    int m = m0 + row;
    int b = m / NPATCH, p = m - b * NPATCH;
    int py = p / 14, px = p - py * 14;
    abase[it] = (long)(b * 3) * 50176 + (py * 16) * 224 + px * 16;
    aldso[it] = row * 72 + kpos * 2;
  }
  long woff[2]; int wofs[2];
  #pragma unroll
  for (int r = 0; r < 2; ++r) {
    int off = r * 4096 + tid * 16;
    int row = off >> 6;
    int c16 = (off >> 4) & 3;
    int kk = (c16 ^ fsw(row)) << 3;
    woff[r] = (long)(n0 + row) * CONVK + kk;
    wofs[r] = off;
  }
  #pragma unroll
  for (int r = 0; r < 2; ++r) {
    gload16(cwh + woff[r], (char*)Wbuf + wofs[r]);
    gload16(cwl + woff[r], (char*)Wbuf + 8192 + wofs[r]);
  }
  float4 xr[4];
  {
    int c = kpos >> 8, r8 = kpos & 255;
    long soff = (long)c * 50176 + (r8 >> 4) * 224 + (r8 & 15);
    #pragma unroll
    for (int it = 0; it < 4; ++it) xr[it] = *(const float4*)&x[abase[it] + soff];
  }
  int cur = 0;
  for (int kc = 0; kc < CONVK; kc += 32) {
    #pragma unroll
    for (int it = 0; it < 4; ++it) {
      float vv[4] = {xr[it].x, xr[it].y, xr[it].z, xr[it].w};
      u16 h[4], l[4];
      #pragma unroll
      for (int j = 0; j < 4; ++j) {
        h[j] = f2b(vv[j]);
        l[j] = f2b(vv[j] - b2f(h[j]));
      }
      *(uint2*)((char*)Ah_s + aldso[it]) = *(const uint2*)h;
      *(uint2*)((char*)Al_s + aldso[it]) = *(const uint2*)l;
    }
    __syncthreads();                         // bar1 (ds_write visible)
    if (kc + 32 < CONVK) {                   // prefetch next W + x under MFMA
      char* wdst = (char*)Wbuf + ((cur ^ 1) << 14);
      #pragma unroll
      for (int r = 0; r < 2; ++r) {
        gload16(cwh + woff[r] + kc + 32, wdst + wofs[r]);
        gload16(cwl + woff[r] + kc + 32, wdst + 8192 + wofs[r]);
      }
      int k = kc + 32 + kpos;
      int c = k >> 8, r8 = k & 255;
      long soff = (long)c * 50176 + (r8 >> 4) * 224 + (r8 & 15);
      #pragma unroll
      for (int it = 0; it < 4; ++it) xr[it] = *(const float4*)&x[abase[it] + soff];
    }
    const char* Wcur = (const char*)Wbuf + (cur << 14);
    s16x8 ah[4], al[4], bh[4], bl[4];
    #pragma unroll
    for (int i = 0; i < 4; ++i) {
      int rowa = wr * 64 + i * 16 + l15;
      ah[i] = ldA72(Ah_s, rowa, l4);
      al[i] = ldA72(Al_s, rowa, l4);
      int rowb = wc * 64 + i * 16 + l15;
      int kbb = (l4 ^ fsw(rowb)) << 4;
      bh[i] = *(const s16x8*)(Wcur + rowb * 64 + kbb);
      bl[i] = *(const s16x8*)(Wcur + 8192 + rowb * 64 + kbb);
    }
    #pragma unroll
    for (int i = 0; i < 4; ++i)
      #pragma unroll
      for (int j = 0; j < 4; ++j)
        acc[i][j] = __builtin_amdgcn_mfma_f32_16x16x32_bf16(ah[i], bh[j],
                                                            acc[i][j], 0, 0, 0);
    #pragma unroll
    for (int i = 0; i < 4; ++i)
      #pragma unroll
      for (int j = 0; j < 4; ++j)
        acc[i][j] = __builtin_amdgcn_mfma_f32_16x16x32_bf16(ah[i], bl[j],
                                                            acc[i][j], 0, 0, 0);
    #pragma unroll
    for (int i = 0; i < 4; ++i)
      #pragma unroll
      for (int j = 0; j < 4; ++j)
        acc[i][j] = __builtin_amdgcn_mfma_f32_16x16x32_bf16(al[i], bh[j],
                                                            acc[i][j], 0, 0, 0);
    __syncthreads();                         // bar2 (drains prefetch under MFMA)
    cur ^= 1;
  }
  const int mb = m0 + wr * 64 + (l4 << 2);
  const int nb = n0 + wc * 64 + l15;
  #pragma unroll
  for (int i = 0; i < 4; ++i) {
    #pragma unroll
    for (int jf = 0; jf < 4; ++jf) {
      #pragma unroll
      for (int j = 0; j < 4; ++j) {
        int m = mb + i * 16 + j;
        int n = nb + jf * 16;
        int bq = m / NPATCH;
        long cr = (long)bq * SEQL + (m - bq * NPATCH) + 1;
        tok[cr * DMODEL + n] = acc[i][jf][j] + cb[n];
      }
    }
  }
}

// ---------------- LN1 stats for all rows; writes cls rows into tok -----------
__global__ __launch_bounds__(256) void k_lnstat(const float* __restrict__ cls,
                                                float* __restrict__ tok,
                                                float2* __restrict__ st) {
  const int row = blockIdx.x * 4 + (threadIdx.x >> 6);
  const int lane = threadIdx.x & 63;
  const int b = row / SEQL, s = row - b * SEQL;
  float vv[4];
  if (s == 0) {
    *(float4*)vv = *(const float4*)&cls[lane * 4];
    *(float4*)&tok[(size_t)row * DMODEL + lane * 4] = *(const float4*)vv;
  } else {
    *(float4*)vv = *(const float4*)&tok[(size_t)row * DMODEL + lane * 4];
  }
  float s1 = vv[0] + vv[1] + vv[2] + vv[3];
  float s2 = vv[0]*vv[0] + vv[1]*vv[1] + vv[2]*vv[2] + vv[3]*vv[3];
  s1 = warp_sum(s1);
  s2 = warp_sum(s2);
  if (lane == 0) {
    float mu = s1 * (1.f / DMODEL);
    float var = s2 * (1.f / DMODEL) - mu * mu;
    st[row] = make_float2(mu, rsqrtf(var + 1e-5f));
  }
}

// ---------------- fused LN1 + K/V split-MFMA GEMM, tile 128x128 --------------
// 1D grid 788 with bijective XCD swizzle (q=98, r=4).
__global__ __launch_bounds__(256) void k_qkv(const float* __restrict__ tok,
                                             const float2* __restrict__ stats,
                                             const float* __restrict__ g,
                                             const float* __restrict__ bb,
                                             const u16* __restrict__ Wh,
                                             const u16* __restrict__ Wl,
                                             const float* __restrict__ bias,
                                             float* __restrict__ Cf) {
  const int lin = blockIdx.x;
  const int xcd = lin & 7, j = lin >> 3;
  const int base = (xcd < 4) ? xcd * 99 : 396 + (xcd - 4) * 98;
  const int wid = base + j;
  const int n0 = (wid & 3) * 128;
  const int m0 = (wid >> 2) * 128;
  __shared__ __align__(16) u16 lds[25600];
  u16* Ah_s = lds;
  u16* Al_s = lds + 4608;
  u16* Wbuf = lds + 9216;
  const int tid = threadIdx.x;
  const int lane = tid & 63;
  const int wv = tid >> 6;
  const int wr = wv >> 1, wc = wv & 1;
  const int l15 = lane & 15, l4 = lane >> 4;
  f32x4 acc[4][4] = {};

  const int kpos = (tid & 7) * 4;
  long atok[4]; float2 st[4]; int aldso[4];
  #pragma unroll
  for (int it = 0; it < 4; ++it) {
    int row = it * 32 + (tid >> 3);
    int m = m0 + row;
    atok[it] = (long)m * DMODEL;
    st[it] = stats[m];
    aldso[it] = row * 72 + kpos * 2;
  }
  long woff[2]; int wofs[2];
  #pragma unroll
  for (int r = 0; r < 2; ++r) {
    int off = r * 4096 + tid * 16;
    int row = off >> 6;
    int c16 = (off >> 4) & 3;
    int kk = (c16 ^ fsw(row)) << 3;
    woff[r] = (long)(n0 + row) * DMODEL + kk;
    wofs[r] = off;
  }
  #pragma unroll
  for (int r = 0; r < 2; ++r) {
    gload16(Wh + woff[r], (char*)Wbuf + wofs[r]);
    gload16(Wl + woff[r], (char*)Wbuf + 8192 + wofs[r]);
  }
  float4 xr[4], gr, br;
  #pragma unroll
  for (int it = 0; it < 4; ++it) xr[it] = *(const float4*)&tok[atok[it] + kpos];
  gr = *(const float4*)&g[kpos];
  br = *(const float4*)&bb[kpos];
  int cur = 0;
  for (int kc = 0; kc < DMODEL; kc += 32) {
    float gg[4] = {gr.x, gr.y, gr.z, gr.w};
    float bbv[4] = {br.x, br.y, br.z, br.w};
    #pragma unroll
    for (int it = 0; it < 4; ++it) {
      float vv[4] = {xr[it].x, xr[it].y, xr[it].z, xr[it].w};
      u16 h[4], l[4];
      #pragma unroll
      for (int j2 = 0; j2 < 4; ++j2) {
        float xd = (vv[j2] - st[it].x) * st[it].y * gg[j2] + bbv[j2];
        h[j2] = f2b(xd);
        l[j2] = f2b(xd - b2f(h[j2]));
      }
      *(uint2*)((char*)Ah_s + aldso[it]) = *(const uint2*)h;
      *(uint2*)((char*)Al_s + aldso[it]) = *(const uint2*)l;
    }
    __syncthreads();
    if (kc + 32 < DMODEL) {
      char* wdst = (char*)Wbuf + ((cur ^ 1) << 14);
      #pragma unroll
      for (int r = 0; r < 2; ++r) {
        gload16(Wh + woff[r] + kc + 32, wdst + wofs[r]);
        gload16(Wl + woff[r] + kc + 32, wdst + 8192 + wofs[r]);
      }
      #pragma unroll
      for (int it = 0; it < 4; ++it)
        xr[it] = *(const float4*)&tok[atok[it] + kc + 32 + kpos];
      gr = *(const float4*)&g[kc + 32 + kpos];
      br = *(const float4*)&bb[kc + 32 + kpos];
    }
    const char* Wcur = (const char*)Wbuf + (cur << 14);
    s16x8 ah[4], al[4], bh[4], bl[4];
    #pragma unroll
    for (int i = 0; i < 4; ++i) {
      int rowa = wr * 64 + i * 16 + l15;
      ah[i] = ldA72(Ah_s, rowa, l4);
      al[i] = ldA72(Al_s, rowa, l4);
      int rowb = wc * 64 + i * 16 + l15;
      int kbb = (l4 ^ fsw(rowb)) << 4;
      bh[i] = *(const s16x8*)(Wcur + rowb * 64 + kbb);
      bl[i] = *(const s16x8*)(Wcur + 8192 + rowb * 64 + kbb);
    }
    #pragma unroll
    for (int i = 0; i < 4; ++i)
      #pragma unroll
      for (int j2 = 0; j2 < 4; ++j2)
        acc[i][j2] = __builtin_amdgcn_mfma_f32_16x16x32_bf16(ah[i], bh[j2],
                                                             acc[i][j2], 0, 0, 0);
    #pragma unroll
    for (int i = 0; i < 4; ++i)
      #pragma unroll
      for (int j2 = 0; j2 < 4; ++j2)
        acc[i][j2] = __builtin_amdgcn_mfma_f32_16x16x32_bf16(ah[i], bl[j2],
                                                             acc[i][j2], 0, 0, 0);
    #pragma unroll
    for (int i = 0; i < 4; ++i)
      #pragma unroll
      for (int j2 = 0; j2 < 4; ++j2)
        acc[i][j2] = __builtin_amdgcn_mfma_f32_16x16x32_bf16(al[i], bh[j2],
                                                             acc[i][j2], 0, 0, 0);
    __syncthreads();
    cur ^= 1;
  }
  const int mb = m0 + wr * 64 + (l4 << 2);
  const int nb = n0 + wc * 64 + l15;
  #pragma unroll
  for (int i = 0; i < 4; ++i) {
    #pragma unroll
    for (int jf = 0; jf < 4; ++jf) {
      #pragma unroll
      for (int j2 = 0; j2 < 4; ++j2) {
        int m = mb + i * 16 + j2;
        int n = nb + jf * 16;
        Cf[(long)m * 512 + n] = acc[i][jf][j2] + bias[n];
      }
    }
  }
}

// ---------------- attention v3: one block per (b,h), 256 thr -----------------
__global__ __launch_bounds__(256) void k_attn2(const float* __restrict__ qf,
                                               const float* __restrict__ kvf,
                                               float* __restrict__ aocf) {
  const int b = blockIdx.x, h = blockIdx.y;
  const int tid = threadIdx.x, w = tid >> 6, lane = tid & 63;
  __shared__ float qs[32];
  __shared__ float Ps[256];
  __shared__ float red[8];
  __shared__ float pvred[8][32];
  if (tid < 32) qs[tid] = qf[h * 32 + tid];
  __syncthreads();
  float s = -1e30f;
  if (tid < SEQL) {
    const float* kr = kvf + ((size_t)(b * SEQL + tid)) * 512 + h * 32;
    float a = 0.f;
    #pragma unroll
    for (int i = 0; i < 8; ++i) {
      float4 k4 = *(const float4*)(kr + i * 4);
      a = fmaf(k4.x, qs[i * 4 + 0], a);
      a = fmaf(k4.y, qs[i * 4 + 1], a);
      a = fmaf(k4.z, qs[i * 4 + 2], a);
      a = fmaf(k4.w, qs[i * 4 + 3], a);
    }
    s = a * 0.17677669529663687f;  // 1/sqrt(32)
  }
  float mx = warp_max(s);
  if (lane == 0) red[w] = mx;
  __syncthreads();
  mx = fmaxf(fmaxf(red[0], red[1]), fmaxf(red[2], red[3]));
  float e = (tid < SEQL) ? __expf(s - mx) : 0.f;
  float ssum = warp_sum(e);
  if (lane == 0) red[4 + w] = ssum;
  __syncthreads();
  float inv = 1.f / (red[4] + red[5] + red[6] + red[7]);
  Ps[tid] = e * inv;
  __syncthreads();
  const int d = tid & 31, kq = tid >> 5;
  float acc = 0.f;
  const int kbeg = kq * 25;
  #pragma unroll 5
  for (int i = 0; i < 25; ++i) {
    int k = kbeg + i;
    if (k < SEQL)
      acc = fmaf(Ps[k], kvf[((size_t)(b * SEQL + k)) * 512 + 256 + h * 32 + d], acc);
  }
  pvred[kq][d] = acc;
  __syncthreads();
  if (tid < 32) {
    float r = 0.f;
    #pragma unroll
    for (int j = 0; j < 8; ++j) r += pvred[j][tid];
    aocf[b * DMODEL + h * 32 + tid] = r;
  }
}

// ---------------- fused oproj + residual(cls) + LN2 + router + MoE1 ----------
__global__ __launch_bounds__(512) void k_tail2(
    const float* __restrict__ aocf,
    const float* __restrict__ ow, const float* __restrict__ ob,
    const float* __restrict__ cls,
    const float* __restrict__ g, const float* __restrict__ bb,
    const float* __restrict__ rw, const float* __restrict__ rb,
    const float* __restrict__ w1, const float* __restrict__ b1,
    float* __restrict__ tokc, float* __restrict__ maskf,
    float* __restrict__ hid) {
  const int b = blockIdx.x;
  const int tid = threadIdx.x, w = tid >> 6, lane = tid & 63;
  __shared__ float aos[DMODEL];
  __shared__ float xd_s[DMODEL];
  __shared__ float red[8];
  __shared__ float lg[4];
  __shared__ float mk[4];
  __shared__ int epair[2];

  if (tid < 256) aos[tid] = aocf[b * DMODEL + tid];
  __syncthreads();

  float t_ = 0.f;
  if (tid < 256) {
    float val = ob[tid];
    #pragma unroll 4
    for (int i = 0; i < 64; ++i) {
      float4 wv2 = *(const float4*)(ow + (size_t)tid * DMODEL + i * 4);
      val = fmaf(wv2.x, aos[i * 4 + 0], val);
      val = fmaf(wv2.y, aos[i * 4 + 1], val);
      val = fmaf(wv2.z, aos[i * 4 + 2], val);
      val = fmaf(wv2.w, aos[i * 4 + 3], val);
    }
    t_ = cls[tid] + val;
    tokc[b * DMODEL + tid] = t_;
  }
  float s1 = warp_sum(t_), s2 = warp_sum(t_ * t_);
  if (tid < 256 && lane == 0) { red[w] = s1; red[4 + w] = s2; }
  __syncthreads();
  s1 = red[0] + red[1] + red[2] + red[3];
  s2 = red[4] + red[5] + red[6] + red[7];
  float mu = s1 * (1.f / DMODEL);
  float var = s2 * (1.f / DMODEL) - mu * mu;
  float rs = rsqrtf(var + 1e-5f);
  if (tid < 256) xd_s[tid] = (t_ - mu) * rs * g[tid] + bb[tid];
  __syncthreads();

  if (tid < 256) {
    float s = 0.f;
    #pragma unroll
    for (int i = 0; i < 4; ++i)
      s = fmaf(xd_s[lane + i * 64], rw[w * DMODEL + lane + i * 64], s);
    s = warp_sum(s) + rb[w];
    if (lane == 0) lg[w] = s;
  }
  __syncthreads();
  if (tid < NEXP) {
    int e = tid;
    int rank = 0;
    #pragma unroll
    for (int j = 0; j < NEXP; ++j)
      if (j != e && (lg[j] > lg[e] || (lg[j] == lg[e] && j < e))) ++rank;
    float m = (rank < 2) ? 1.f : 0.f;
    mk[e] = m;
    maskf[b * NEXP + e] = m;
  }
  __syncthreads();
  if (tid == 0) {
    int e0 = 0;
    while (e0 < 3 && mk[e0] == 0.f) ++e0;
    int e1 = e0 + 1;
    while (e1 < 3 && mk[e1] == 0.f) ++e1;
    epair[0] = e0; epair[1] = e1;
  }
  __syncthreads();

  const int e0 = epair[0], e1 = epair[1];
  const float* w1a = w1 + (size_t)e0 * DMODEL * FFD + tid;
  const float* w1b = w1 + (size_t)e1 * DMODEL * FFD + tid;
  float a0 = 0.f, a1 = 0.f, a2 = 0.f, a3 = 0.f;
  #pragma unroll 4
  for (int k = 0; k < DMODEL; ++k) {
    float xv = xd_s[k];
    const float* ra = w1a + (size_t)k * FFD;
    const float* rb2 = w1b + (size_t)k * FFD;
    a0 = fmaf(xv, ra[0], a0);
    a1 = fmaf(xv, ra[512], a1);
    a2 = fmaf(xv, rb2[0], a2);
    a3 = fmaf(xv, rb2[512], a3);
  }
  float* h0 = hid + ((size_t)e0 * NBATCH + b) * FFD;
  float* h1 = hid + ((size_t)e1 * NBATCH + b) * FFD;
  float v0 = a0 + b1[e0 * FFD + tid];
  float v1 = a1 + b1[e0 * FFD + tid + 512];
  float v2 = a2 + b1[e1 * FFD + tid];
  float v3 = a3 + b1[e1 * FFD + tid + 512];
  h0[tid]       = 0.5f * v0 * (1.0f + erff(v0 * 0.70710678118654752f));
  h0[tid + 512] = 0.5f * v1 * (1.0f + erff(v1 * 0.70710678118654752f));
  h1[tid]       = 0.5f * v2 * (1.0f + erff(v2 * 0.70710678118654752f));
  h1[tid + 512] = 0.5f * v3 * (1.0f + erff(v3 * 0.70710678118654752f));
}

// ---------------- MoE GEMM2 (parallel): block per (token, dchunk) ------------
__global__ __launch_bounds__(256) void k_moe2(const float* __restrict__ hid,
                                              const float* __restrict__ w2,
                                              const float* __restrict__ b2,
                                              const float* __restrict__ maskf,
                                              float* __restrict__ tokc) {
  const int t = blockIdx.x, dc = blockIdx.y;
  const int tid = threadIdx.x;
  const int dl = tid & 127, kh = tid >> 7;
  const int dout = dc * 128 + dl;
  int e0 = 0;
  while (e0 < 3 && maskf[t * NEXP + e0] == 0.f) ++e0;
  int e1 = e0 + 1;
  while (e1 < 3 && maskf[t * NEXP + e1] == 0.f) ++e1;
  __shared__ float hs0[FFD], hs1[FFD];
  const float* h0 = hid + ((size_t)e0 * NBATCH + t) * FFD;
  const float* h1 = hid + ((size_t)e1 * NBATCH + t) * FFD;
  for (int i = tid * 4; i < FFD; i += 1024) {
    *(float4*)&hs0[i] = *(const float4*)&h0[i];
    *(float4*)&hs1[i] = *(const float4*)&h1[i];
  }
  __syncthreads();
  const float* w20 = w2 + (size_t)e0 * FFD * DMODEL + dout;
  const float* w21 = w2 + (size_t)e1 * FFD * DMODEL + dout;
  float a0 = 0.f, a1 = 0.f;
  const int k0 = kh * 512;
  #pragma unroll 8
  for (int k = k0; k < k0 + 512; ++k) {
    a0 = fmaf(hs0[k], w20[(size_t)k * DMODEL], a0);
    a1 = fmaf(hs1[k], w21[(size_t)k * DMODEL], a1);
  }
  __shared__ float red[256];
  red[tid] = a0 + a1;
  __syncthreads();
  if (kh == 0) {
    float full = red[dl] + red[128 + dl] +
                 b2[e0 * DMODEL + dout] + b2[e1 * DMODEL + dout];
    tokc[t * DMODEL + dout] += full;
  }
}

// ---------------- classifier head on compact tokc ----------------------------
__global__ __launch_bounds__(256) void k_head(const float* __restrict__ tokc,
                                              const float* __restrict__ hw,
                                              const float* __restrict__ hb,
                                              float* __restrict__ out) {
  int b = blockIdx.x;
  int w = threadIdx.x >> 6, lane = threadIdx.x & 63;
  const float* row = tokc + (size_t)b * DMODEL;
  for (int c = w; c < NCLS; c += 4) {
    float s = 0.f;
    for (int d = lane; d < DMODEL; d += 64) s = fmaf(row[d], hw[c * DMODEL + d], s);
    s = warp_sum(s);
    if (lane == 0) out[b * NCLS + c] = s + hb[c];
  }
}

extern "C" void kernel_launch(void* const* d_in, const int* in_sizes, int n_in,
                              void* d_out, int out_size, void* d_ws, size_t ws_size,
                              hipStream_t stream) {
  const float* x      = (const float*)d_in[0];
  const float* conv_w = (const float*)d_in[1];
  const float* conv_b = (const float*)d_in[2];
  const float* cls    = (const float*)d_in[3];
  const float* ln1g   = (const float*)d_in[4];
  const float* ln1b   = (const float*)d_in[5];
  const float* qkv_w  = (const float*)d_in[6];
  const float* qkv_b  = (const float*)d_in[7];
  const float* out_w  = (const float*)d_in[8];
  const float* out_b  = (const float*)d_in[9];
  const float* ln2g   = (const float*)d_in[10];
  const float* ln2b   = (const float*)d_in[11];
  const float* rw     = (const float*)d_in[12];
  const float* rb     = (const float*)d_in[13];
  const float* e_w1   = (const float*)d_in[14];
  const float* e_b1   = (const float*)d_in[15];
  const float* e_w2   = (const float*)d_in[16];
  const float* e_b2   = (const float*)d_in[17];
  const float* head_w = (const float*)d_in[18];
  const float* head_b = (const float*)d_in[19];
  float* out = (float*)d_out;

  char* ws = (char*)d_ws;
  size_t off = 0;
  auto alloc = [&](size_t bytes) {
    void* p = ws + off;
    off += (bytes + 255) & ~(size_t)255;
    return p;
  };
  float*  tok   = (float*)alloc((size_t)TTOK * DMODEL * 4);    // 25.8 MB
  float*  qkvf  = (float*)alloc((size_t)TTOK * 512 * 4);       // 51.6 (K|V fp32)
  float2* stats = (float2*)alloc((size_t)TTOK * 8);            // 0.2
  u16*    cwh   = (u16*)alloc((size_t)DMODEL * CONVK * 2);
  u16*    cwl   = (u16*)alloc((size_t)DMODEL * CONVK * 2);
  u16*    qwh   = (u16*)alloc((size_t)768 * DMODEL * 2);
  u16*    qwl   = (u16*)alloc((size_t)768 * DMODEL * 2);
  float*  qf    = (float*)alloc((size_t)DMODEL * 4);
  float*  aocf  = (float*)alloc((size_t)NBATCH * DMODEL * 4);
  float*  tokc  = (float*)alloc((size_t)NBATCH * DMODEL * 4);
  float*  maskf = (float*)alloc((size_t)NBATCH * NEXP * 4);
  float*  hid   = (float*)alloc((size_t)NEXP * NBATCH * FFD * 4);  // 2 MB

  // weight splits + q_cls (block 384)
  k_cast2b<<<385, 256, 0, stream>>>(conv_w, cwh, cwl, qkv_w, qwh, qwl,
                                    cls, ln1g, ln1b, qkv_b, qf);

  // conv GEMM (proven config, 128x128, XCD-swizzled 1D grid 392) -> tok (CMAP)
  k_conv<<<392, 256, 0, stream>>>(x, cwh, cwl, conv_b, tok);

  // cls rows into tok + LN1 stats for all rows
  k_lnstat<<<TTOK / 4, 256, 0, stream>>>(cls, tok, stats);

  // fused LN1 + K,V projection (XCD-swizzled 1D grid 788) -> fp32 [TTOK][512]
  k_qkv<<<788, 256, 0, stream>>>(
      tok, stats, ln1g, ln1b, qwh + 256 * DMODEL, qwl + 256 * DMODEL,
      qkv_b + 256, qkvf);

  // attention: 1024 blocks (b,h), high occupancy streaming
  k_attn2<<<dim3(NBATCH, NHEADS), 256, 0, stream>>>(qf, qkvf, aocf);

  // oproj + residual + LN2 + router + MoE1, one block per batch
  k_tail2<<<NBATCH, 512, 0, stream>>>(aocf, out_w, out_b, cls,
                                      ln2g, ln2b, rw, rb,
                                      e_w1, e_b1, tokc, maskf, hid);

  // MoE GEMM2 (proven parallel config) + head
  k_moe2<<<dim3(NBATCH, 2), 256, 0, stream>>>(hid, e_w2, e_b2, maskf, tokc);
  k_head<<<NBATCH, 256, 0, stream>>>(tokc, head_w, head_b, out);
}